// Round 8
// baseline (135.675 us; speedup 1.0000x reference)
//
#include <hip/hip_runtime.h>
#include <hip/hip_bf16.h>

#define D 128
#define TM 32
#define PAD 8

typedef unsigned int u32;
typedef unsigned short u16;
typedef __attribute__((ext_vector_type(8))) short short8;
typedef __attribute__((ext_vector_type(4))) float f32x4;
typedef __attribute__((ext_vector_type(4))) unsigned int u32x4;
typedef __attribute__((ext_vector_type(4))) unsigned short u16x4;

static __device__ __forceinline__ u16 f2b(float x) {
  __hip_bfloat16 b = __float2bfloat16(x);
  return *reinterpret_cast<u16*>(&b);
}
static __device__ __forceinline__ float u2f(u32 x) { return __uint_as_float(x); }

// ---------- bf16 fast path ----------

// Wt[c,k] = bf16(W[k,c])  (run once; 16K threads)
__global__ __launch_bounds__(256) void cvt_w(const float* __restrict__ W,
                                             u16* __restrict__ Wt) {
  int i = blockIdx.x * 256 + threadIdx.x;
  if (i >= D * D) return;
  int k = i >> 7, c = i & (D - 1);
  Wt[c * D + k] = f2b(W[k * D + c]);
}

// Yb[r,:] = bf16( src_norm[r] * (X[r,:] @ W) )   (64-row tile per block)
// A staged in LDS (17 KB); B fragments read from global Wt (32 KB, L1-hot).
__global__ __launch_bounds__(256) void gemm_xw(
    const float* __restrict__ X, const float* __restrict__ sn,
    const u16* __restrict__ Wt, u16* __restrict__ Yb, int n) {
  __shared__ u16 Asl[64][D + PAD];
  int tid = threadIdx.x;
  int r0 = blockIdx.x * 64;

#pragma unroll
  for (int p = 0; p < 8; ++p) {  // stage A tile with ns scale + cvt
    int idx = p * 256 + tid;
    int row = idx >> 5, c0 = (idx & 31) << 2;
    int gr = r0 + row;
    if (gr >= n) gr = n - 1;
    float ns = sn[gr];
    f32x4 v = __builtin_nontemporal_load(
        reinterpret_cast<const f32x4*>(X + (size_t)gr * D + c0));
    u16x4 o;
    o.x = f2b(v.x * ns); o.y = f2b(v.y * ns);
    o.z = f2b(v.z * ns); o.w = f2b(v.w * ns);
    *reinterpret_cast<u16x4*>(&Asl[row][c0]) = o;
  }
  __syncthreads();

  int wv = tid >> 6, lane = tid & 63;
  int lr = lane & 15, lg = lane >> 4;
  int arow = wv * 16 + lr;

  f32x4 acc[8] = {};
#pragma unroll
  for (int ks = 0; ks < 4; ++ks) {
    int k0 = ks * 32 + lg * 4;
    union { uint2 u[2]; short8 s; } pa;
    pa.u[0] = *reinterpret_cast<const uint2*>(&Asl[arow][k0]);
    pa.u[1] = *reinterpret_cast<const uint2*>(&Asl[arow][k0 + 16]);
#pragma unroll
    for (int nn = 0; nn < 8; ++nn) {
      union { uint2 u[2]; short8 s; } pb;
      pb.u[0] = *reinterpret_cast<const uint2*>(Wt + (nn * 16 + lr) * D + k0);
      pb.u[1] = *reinterpret_cast<const uint2*>(Wt + (nn * 16 + lr) * D + k0 + 16);
      acc[nn] = __builtin_amdgcn_mfma_f32_16x16x32_bf16(pa.s, pb.s, acc[nn], 0, 0, 0);
    }
  }

  __syncthreads();  // Asl reads done; reuse it to repack output as bf16
#pragma unroll
  for (int nn = 0; nn < 8; ++nn)
#pragma unroll
    for (int r = 0; r < 4; ++r)
      Asl[wv * 16 + lg * 4 + r][nn * 16 + lr] = f2b(acc[nn][r]);
  __syncthreads();

#pragma unroll
  for (int p = 0; p < 4; ++p) {  // coalesced 16-B NT stores
    int idx = p * 256 + tid;
    int row = idx >> 4, c8 = (idx & 15) << 3;
    int gr = r0 + row;
    if (gr < n)
      __builtin_nontemporal_store(
          *reinterpret_cast<const u32x4*>(&Asl[row][c8]),
          reinterpret_cast<u32x4*>(Yb + (size_t)gr * D + c8));
  }
}

#define ACC8(r)                                             \
  a0 += u2f(r.x << 16); a1 += u2f(r.x & 0xffff0000u);       \
  a2 += u2f(r.y << 16); a3 += u2f(r.y & 0xffff0000u);       \
  a4 += u2f(r.z << 16); a5 += u2f(r.z & 0xffff0000u);       \
  a6 += u2f(r.w << 16); a7 += u2f(r.w & 0xffff0000u);

// out[node,:] = dst_norm[node] * sum_e Yb[src[e],:]   (f32 output)
// 16 lanes per node, 8 bf16 (16 B) per lane; 16-deep load batch for MLP.
__global__ __launch_bounds__(256) void agg_final(
    const int* __restrict__ edge_ptr, const int* __restrict__ src_edges,
    const float* __restrict__ dst_norm, const u16* __restrict__ Yb,
    float* __restrict__ out, int n_nodes) {
  int gid = blockIdx.x * 256 + threadIdx.x;
  int node = gid >> 4;
  if (node >= n_nodes) return;
  int fo = (gid & 15) << 3;
  const u16* base = Yb + fo;
  float a0 = 0, a1 = 0, a2 = 0, a3 = 0, a4 = 0, a5 = 0, a6 = 0, a7 = 0;
  int e0 = edge_ptr[node], e1 = edge_ptr[node + 1];
  int e = e0;
  for (; e + 16 <= e1; e += 16) {
    int s[16];
#pragma unroll
    for (int j = 0; j < 16; ++j) s[j] = src_edges[e + j];
    uint4 r[16];
#pragma unroll
    for (int j = 0; j < 16; ++j)
      r[j] = *reinterpret_cast<const uint4*>(base + (size_t)s[j] * D);
#pragma unroll
    for (int j = 0; j < 16; ++j) { ACC8(r[j]); }
  }
  for (; e + 4 <= e1; e += 4) {
    int s0 = src_edges[e + 0], s1 = src_edges[e + 1];
    int s2 = src_edges[e + 2], s3 = src_edges[e + 3];
    uint4 r0v = *reinterpret_cast<const uint4*>(base + (size_t)s0 * D);
    uint4 r1v = *reinterpret_cast<const uint4*>(base + (size_t)s1 * D);
    uint4 r2v = *reinterpret_cast<const uint4*>(base + (size_t)s2 * D);
    uint4 r3v = *reinterpret_cast<const uint4*>(base + (size_t)s3 * D);
    ACC8(r0v); ACC8(r1v); ACC8(r2v); ACC8(r3v);
  }
  for (; e < e1; ++e) {
    int s = src_edges[e];
    uint4 rv = *reinterpret_cast<const uint4*>(base + (size_t)s * D);
    ACC8(rv);
  }
  float nd = dst_norm[node];
  f32x4 o0 = {a0 * nd, a1 * nd, a2 * nd, a3 * nd};
  f32x4 o1 = {a4 * nd, a5 * nd, a6 * nd, a7 * nd};
  float* dst = out + (size_t)node * D + fo;
  __builtin_nontemporal_store(o0, reinterpret_cast<f32x4*>(dst));
  __builtin_nontemporal_store(o1, reinterpret_cast<f32x4*>(dst + 4));
}

// ---------- f32 fallback path (known-good) ----------

__global__ __launch_bounds__(256) void agg_kernel(
    const int* __restrict__ edge_ptr, const int* __restrict__ src_edges,
    const float* __restrict__ src_norm, const float* __restrict__ dst_norm,
    const float* __restrict__ X, float* __restrict__ agg, int n_nodes) {
  int gid = blockIdx.x * 256 + threadIdx.x;
  int node = gid >> 5;
  if (node >= n_nodes) return;
  int fo = (gid & 31) << 2;
  int e0 = edge_ptr[node];
  int e1 = edge_ptr[node + 1];
  float ax = 0.f, ay = 0.f, az = 0.f, aw = 0.f;
  for (int e = e0; e < e1; ++e) {
    int s = src_edges[e];
    float ns = src_norm[s];
    float4 v = *reinterpret_cast<const float4*>(X + (size_t)s * D + fo);
    ax = fmaf(ns, v.x, ax); ay = fmaf(ns, v.y, ay);
    az = fmaf(ns, v.z, az); aw = fmaf(ns, v.w, aw);
  }
  float nd = dst_norm[node];
  float4 r = make_float4(ax * nd, ay * nd, az * nd, aw * nd);
  *reinterpret_cast<float4*>(agg + (size_t)node * D + fo) = r;
}

#define FMA4(acc, sv, wv)            \
  acc.x = fmaf(sv, wv.x, acc.x);     \
  acc.y = fmaf(sv, wv.y, acc.y);     \
  acc.z = fmaf(sv, wv.z, acc.z);     \
  acc.w = fmaf(sv, wv.w, acc.w);

__global__ __launch_bounds__(256) void gemm_kernel(
    float* __restrict__ io, const float* __restrict__ W, int n_rows) {
  __shared__ float Wl[D][D];
  __shared__ float Al[TM][D];
  int tid = threadIdx.x;
  for (int i = tid * 4; i < D * D; i += 1024) {
    *reinterpret_cast<float4*>(&Wl[0][0] + i) =
        *reinterpret_cast<const float4*>(W + i);
  }
  int row0 = blockIdx.x * TM;
  for (int i = tid * 4; i < TM * D; i += 1024) {
    int r = i >> 7, c = i & (D - 1);
    if (row0 + r < n_rows)
      *reinterpret_cast<float4*>(&Al[r][c]) =
          *reinterpret_cast<const float4*>(io + (size_t)(row0 + r) * D + c);
  }
  __syncthreads();

  int cg = (tid & 31) * 4;
  int rb = (tid >> 5) * 4;
  float4 acc0 = {0, 0, 0, 0}, acc1 = {0, 0, 0, 0};
  float4 acc2 = {0, 0, 0, 0}, acc3 = {0, 0, 0, 0};

#pragma unroll 4
  for (int k = 0; k < D; k += 4) {
    float4 w0 = *reinterpret_cast<const float4*>(&Wl[k + 0][cg]);
    float4 w1 = *reinterpret_cast<const float4*>(&Wl[k + 1][cg]);
    float4 w2 = *reinterpret_cast<const float4*>(&Wl[k + 2][cg]);
    float4 w3 = *reinterpret_cast<const float4*>(&Wl[k + 3][cg]);
    float4 a0 = *reinterpret_cast<const float4*>(&Al[rb + 0][k]);
    float4 a1 = *reinterpret_cast<const float4*>(&Al[rb + 1][k]);
    float4 a2 = *reinterpret_cast<const float4*>(&Al[rb + 2][k]);
    float4 a3 = *reinterpret_cast<const float4*>(&Al[rb + 3][k]);
    FMA4(acc0, a0.x, w0); FMA4(acc0, a0.y, w1); FMA4(acc0, a0.z, w2); FMA4(acc0, a0.w, w3);
    FMA4(acc1, a1.x, w0); FMA4(acc1, a1.y, w1); FMA4(acc1, a1.z, w2); FMA4(acc1, a1.w, w3);
    FMA4(acc2, a2.x, w0); FMA4(acc2, a2.y, w1); FMA4(acc2, a2.z, w2); FMA4(acc2, a2.w, w3);
    FMA4(acc3, a3.x, w0); FMA4(acc3, a3.y, w1); FMA4(acc3, a3.z, w2); FMA4(acc3, a3.w, w3);
  }

  int r0 = row0 + rb;
  if (r0 + 0 < n_rows) *reinterpret_cast<float4*>(io + (size_t)(r0 + 0) * D + cg) = acc0;
  if (r0 + 1 < n_rows) *reinterpret_cast<float4*>(io + (size_t)(r0 + 1) * D + cg) = acc1;
  if (r0 + 2 < n_rows) *reinterpret_cast<float4*>(io + (size_t)(r0 + 2) * D + cg) = acc2;
  if (r0 + 3 < n_rows) *reinterpret_cast<float4*>(io + (size_t)(r0 + 3) * D + cg) = acc3;
}

extern "C" void kernel_launch(void* const* d_in, const int* in_sizes, int n_in,
                              void* d_out, int out_size, void* d_ws, size_t ws_size,
                              hipStream_t stream) {
  const int* edge_ptr = (const int*)d_in[0];
  const int* src_edges = (const int*)d_in[1];
  const float* src_norm = (const float*)d_in[2];
  const float* dst_norm = (const float*)d_in[3];
  const float* X = (const float*)d_in[5];
  const float* W = (const float*)d_in[6];
  float* out = (float*)d_out;
  int n = in_sizes[2];  // src_norm_degs has N elements

  size_t need = (size_t)n * D * sizeof(u16) + (size_t)D * D * sizeof(u16);
  if (ws_size >= need) {
    u16* Yb = (u16*)d_ws;
    u16* Wt = Yb + (size_t)n * D;
    cvt_w<<<(D * D + 255) / 256, 256, 0, stream>>>(W, Wt);
    gemm_xw<<<(n + 63) / 64, 256, 0, stream>>>(X, src_norm, Wt, Yb, n);
    agg_final<<<(n * 16 + 255) / 256, 256, 0, stream>>>(edge_ptr, src_edges,
                                                        dst_norm, Yb, out, n);
  } else {
    int blocks1 = (n * 32 + 255) / 256;
    agg_kernel<<<blocks1, 256, 0, stream>>>(edge_ptr, src_edges, src_norm,
                                            dst_norm, X, out, n);
    int blocks2 = (n + TM - 1) / TM;
    gemm_kernel<<<blocks2, 256, 0, stream>>>(out, W, n);
  }
}

// Round 9
// 84.010 us; speedup vs baseline: 1.6150x; 1.6150x over previous
//
#include <hip/hip_runtime.h>
#include <hip/hip_bf16.h>

#define D 128
#define TM 32
#define PAD 8

typedef unsigned int u32;
typedef unsigned short u16;
typedef __attribute__((ext_vector_type(8))) short short8;
typedef __attribute__((ext_vector_type(4))) float f32x4;
typedef __attribute__((ext_vector_type(4))) unsigned int u32x4;
typedef __attribute__((ext_vector_type(4))) unsigned short u16x4;

static __device__ __forceinline__ u16 f2b(float x) {
  __hip_bfloat16 b = __float2bfloat16(x);
  return *reinterpret_cast<u16*>(&b);
}
static __device__ __forceinline__ float u2f(u32 x) { return __uint_as_float(x); }

// ---------- bf16 fast path ----------

// Wt[c,k] = bf16(W[k,c])  (run once)
__global__ __launch_bounds__(256) void cvt_w(const float* __restrict__ W,
                                             u16* __restrict__ Wt) {
  int i = blockIdx.x * 256 + threadIdx.x;
  if (i >= D * D) return;
  int k = i >> 7, c = i & (D - 1);
  Wt[c * D + k] = f2b(W[k * D + c]);
}

// Yb[r,:] = bf16( src_norm[r] * (X[r,:] @ W) )   (64-row tile per block)
// Round-3 gemm_mfma structure: Bsl staged from pre-transposed bf16 Wt with
// clean uint4 copies; Asl staged from X with plain f32 loads + ns*cvt.
__global__ __launch_bounds__(256) void gemm_xw(
    const float* __restrict__ X, const float* __restrict__ sn,
    const u16* __restrict__ Wt, u16* __restrict__ Yb, int n) {
  __shared__ u16 Bsl[D][D + PAD];
  __shared__ u16 Asl[64][D + PAD];
  int tid = threadIdx.x;
  int r0 = blockIdx.x * 64;

#pragma unroll
  for (int p = 0; p < 8; ++p) {  // stage Wt (32 KB) - clean 16-B copies
    int t = p * 256 + tid;
    int r = t >> 4, c = (t & 15) << 3;
    *reinterpret_cast<uint4*>(&Bsl[r][c]) =
        *reinterpret_cast<const uint4*>(Wt + r * D + c);
  }
#pragma unroll
  for (int p = 0; p < 8; ++p) {  // stage A tile: f32 load, ns scale, cvt
    int idx = p * 256 + tid;
    int row = idx >> 5, c0 = (idx & 31) << 2;
    int gr = r0 + row;
    if (gr >= n) gr = n - 1;
    float ns = sn[gr];
    f32x4 v = *reinterpret_cast<const f32x4*>(X + (size_t)gr * D + c0);
    u16x4 o;
    o.x = f2b(v.x * ns); o.y = f2b(v.y * ns);
    o.z = f2b(v.z * ns); o.w = f2b(v.w * ns);
    *reinterpret_cast<u16x4*>(&Asl[row][c0]) = o;
  }
  __syncthreads();

  int wv = tid >> 6, lane = tid & 63;
  int lr = lane & 15, lg = lane >> 4;
  int arow = wv * 16 + lr;

  f32x4 acc[8] = {};
#pragma unroll
  for (int ks = 0; ks < 4; ++ks) {
    int k0 = ks * 32 + lg * 4;
    union { uint2 u[2]; short8 s; } pa;
    pa.u[0] = *reinterpret_cast<const uint2*>(&Asl[arow][k0]);
    pa.u[1] = *reinterpret_cast<const uint2*>(&Asl[arow][k0 + 16]);
#pragma unroll
    for (int nn = 0; nn < 8; ++nn) {
      union { uint2 u[2]; short8 s; } pb;
      pb.u[0] = *reinterpret_cast<const uint2*>(&Bsl[nn * 16 + lr][k0]);
      pb.u[1] = *reinterpret_cast<const uint2*>(&Bsl[nn * 16 + lr][k0 + 16]);
      acc[nn] = __builtin_amdgcn_mfma_f32_16x16x32_bf16(pa.s, pb.s, acc[nn], 0, 0, 0);
    }
  }

  __syncthreads();  // Asl reads done; reuse for bf16 output repack
#pragma unroll
  for (int nn = 0; nn < 8; ++nn)
#pragma unroll
    for (int r = 0; r < 4; ++r)
      Asl[wv * 16 + lg * 4 + r][nn * 16 + lr] = f2b(acc[nn][r]);
  __syncthreads();

#pragma unroll
  for (int p = 0; p < 4; ++p) {  // coalesced 16-B NT stores
    int idx = p * 256 + tid;
    int row = idx >> 4, c8 = (idx & 15) << 3;
    int gr = r0 + row;
    if (gr < n)
      __builtin_nontemporal_store(
          *reinterpret_cast<const u32x4*>(&Asl[row][c8]),
          reinterpret_cast<u32x4*>(Yb + (size_t)gr * D + c8));
  }
}

#define ACC8(r)                                             \
  a0 += u2f(r.x << 16); a1 += u2f(r.x & 0xffff0000u);       \
  a2 += u2f(r.y << 16); a3 += u2f(r.y & 0xffff0000u);       \
  a4 += u2f(r.z << 16); a5 += u2f(r.z & 0xffff0000u);       \
  a6 += u2f(r.w << 16); a7 += u2f(r.w & 0xffff0000u);

// out[node,:] = dst_norm[node] * sum_e Yb[src[e],:]  (f32 output)
// Round-3 form: 16 lanes/node, 16 B/lane, 4-deep unroll, low VGPR.
__global__ __launch_bounds__(256) void agg_final(
    const int* __restrict__ edge_ptr, const int* __restrict__ src_edges,
    const float* __restrict__ dst_norm, const u16* __restrict__ Yb,
    float* __restrict__ out, int n_nodes) {
  int gid = blockIdx.x * 256 + threadIdx.x;
  int node = gid >> 4;
  if (node >= n_nodes) return;
  int fo = (gid & 15) << 3;
  const u16* base = Yb + fo;
  float a0 = 0, a1 = 0, a2 = 0, a3 = 0, a4 = 0, a5 = 0, a6 = 0, a7 = 0;
  int e0 = edge_ptr[node], e1 = edge_ptr[node + 1];
  int e = e0;
  for (; e + 4 <= e1; e += 4) {
    int s0 = src_edges[e + 0], s1 = src_edges[e + 1];
    int s2 = src_edges[e + 2], s3 = src_edges[e + 3];
    uint4 r0v = *reinterpret_cast<const uint4*>(base + (size_t)s0 * D);
    uint4 r1v = *reinterpret_cast<const uint4*>(base + (size_t)s1 * D);
    uint4 r2v = *reinterpret_cast<const uint4*>(base + (size_t)s2 * D);
    uint4 r3v = *reinterpret_cast<const uint4*>(base + (size_t)s3 * D);
    ACC8(r0v); ACC8(r1v); ACC8(r2v); ACC8(r3v);
  }
  for (; e < e1; ++e) {
    int s = src_edges[e];
    uint4 rv = *reinterpret_cast<const uint4*>(base + (size_t)s * D);
    ACC8(rv);
  }
  float nd = dst_norm[node];
  f32x4 o0 = {a0 * nd, a1 * nd, a2 * nd, a3 * nd};
  f32x4 o1 = {a4 * nd, a5 * nd, a6 * nd, a7 * nd};
  float* dst = out + (size_t)node * D + fo;
  __builtin_nontemporal_store(o0, reinterpret_cast<f32x4*>(dst));
  __builtin_nontemporal_store(o1, reinterpret_cast<f32x4*>(dst + 4));
}

// ---------- f32 fallback path (known-good) ----------

__global__ __launch_bounds__(256) void agg_kernel(
    const int* __restrict__ edge_ptr, const int* __restrict__ src_edges,
    const float* __restrict__ src_norm, const float* __restrict__ dst_norm,
    const float* __restrict__ X, float* __restrict__ agg, int n_nodes) {
  int gid = blockIdx.x * 256 + threadIdx.x;
  int node = gid >> 5;
  if (node >= n_nodes) return;
  int fo = (gid & 31) << 2;
  int e0 = edge_ptr[node];
  int e1 = edge_ptr[node + 1];
  float ax = 0.f, ay = 0.f, az = 0.f, aw = 0.f;
  for (int e = e0; e < e1; ++e) {
    int s = src_edges[e];
    float ns = src_norm[s];
    float4 v = *reinterpret_cast<const float4*>(X + (size_t)s * D + fo);
    ax = fmaf(ns, v.x, ax); ay = fmaf(ns, v.y, ay);
    az = fmaf(ns, v.z, az); aw = fmaf(ns, v.w, aw);
  }
  float nd = dst_norm[node];
  float4 r = make_float4(ax * nd, ay * nd, az * nd, aw * nd);
  *reinterpret_cast<float4*>(agg + (size_t)node * D + fo) = r;
}

#define FMA4(acc, sv, wv)            \
  acc.x = fmaf(sv, wv.x, acc.x);     \
  acc.y = fmaf(sv, wv.y, acc.y);     \
  acc.z = fmaf(sv, wv.z, acc.z);     \
  acc.w = fmaf(sv, wv.w, acc.w);

__global__ __launch_bounds__(256) void gemm_kernel(
    float* __restrict__ io, const float* __restrict__ W, int n_rows) {
  __shared__ float Wl[D][D];
  __shared__ float Al[TM][D];
  int tid = threadIdx.x;
  for (int i = tid * 4; i < D * D; i += 1024) {
    *reinterpret_cast<float4*>(&Wl[0][0] + i) =
        *reinterpret_cast<const float4*>(W + i);
  }
  int row0 = blockIdx.x * TM;
  for (int i = tid * 4; i < TM * D; i += 1024) {
    int r = i >> 7, c = i & (D - 1);
    if (row0 + r < n_rows)
      *reinterpret_cast<float4*>(&Al[r][c]) =
          *reinterpret_cast<const float4*>(io + (size_t)(row0 + r) * D + c);
  }
  __syncthreads();

  int cg = (tid & 31) * 4;
  int rb = (tid >> 5) * 4;
  float4 acc0 = {0, 0, 0, 0}, acc1 = {0, 0, 0, 0};
  float4 acc2 = {0, 0, 0, 0}, acc3 = {0, 0, 0, 0};

#pragma unroll 4
  for (int k = 0; k < D; k += 4) {
    float4 w0 = *reinterpret_cast<const float4*>(&Wl[k + 0][cg]);
    float4 w1 = *reinterpret_cast<const float4*>(&Wl[k + 1][cg]);
    float4 w2 = *reinterpret_cast<const float4*>(&Wl[k + 2][cg]);
    float4 w3 = *reinterpret_cast<const float4*>(&Wl[k + 3][cg]);
    float4 a0 = *reinterpret_cast<const float4*>(&Al[rb + 0][k]);
    float4 a1 = *reinterpret_cast<const float4*>(&Al[rb + 1][k]);
    float4 a2 = *reinterpret_cast<const float4*>(&Al[rb + 2][k]);
    float4 a3 = *reinterpret_cast<const float4*>(&Al[rb + 3][k]);
    FMA4(acc0, a0.x, w0); FMA4(acc0, a0.y, w1); FMA4(acc0, a0.z, w2); FMA4(acc0, a0.w, w3);
    FMA4(acc1, a1.x, w0); FMA4(acc1, a1.y, w1); FMA4(acc1, a1.z, w2); FMA4(acc1, a1.w, w3);
    FMA4(acc2, a2.x, w0); FMA4(acc2, a2.y, w1); FMA4(acc2, a2.z, w2); FMA4(acc2, a2.w, w3);
    FMA4(acc3, a3.x, w0); FMA4(acc3, a3.y, w1); FMA4(acc3, a3.z, w2); FMA4(acc3, a3.w, w3);
  }

  int r0 = row0 + rb;
  if (r0 + 0 < n_rows) *reinterpret_cast<float4*>(io + (size_t)(r0 + 0) * D + cg) = acc0;
  if (r0 + 1 < n_rows) *reinterpret_cast<float4*>(io + (size_t)(r0 + 1) * D + cg) = acc1;
  if (r0 + 2 < n_rows) *reinterpret_cast<float4*>(io + (size_t)(r0 + 2) * D + cg) = acc2;
  if (r0 + 3 < n_rows) *reinterpret_cast<float4*>(io + (size_t)(r0 + 3) * D + cg) = acc3;
}

extern "C" void kernel_launch(void* const* d_in, const int* in_sizes, int n_in,
                              void* d_out, int out_size, void* d_ws, size_t ws_size,
                              hipStream_t stream) {
  const int* edge_ptr = (const int*)d_in[0];
  const int* src_edges = (const int*)d_in[1];
  const float* src_norm = (const float*)d_in[2];
  const float* dst_norm = (const float*)d_in[3];
  const float* X = (const float*)d_in[5];
  const float* W = (const float*)d_in[6];
  float* out = (float*)d_out;
  int n = in_sizes[2];  // src_norm_degs has N elements

  size_t need = (size_t)n * D * sizeof(u16) + (size_t)D * D * sizeof(u16);
  if (ws_size >= need) {
    u16* Yb = (u16*)d_ws;
    u16* Wt = Yb + (size_t)n * D;
    cvt_w<<<(D * D + 255) / 256, 256, 0, stream>>>(W, Wt);
    gemm_xw<<<(n + 63) / 64, 256, 0, stream>>>(X, src_norm, Wt, Yb, n);
    agg_final<<<(n * 16 + 255) / 256, 256, 0, stream>>>(edge_ptr, src_edges,
                                                        dst_norm, Yb, out, n);
  } else {
    int blocks1 = (n * 32 + 255) / 256;
    agg_kernel<<<blocks1, 256, 0, stream>>>(edge_ptr, src_edges, src_norm,
                                            dst_norm, X, out, n);
    int blocks2 = (n + TM - 1) / TM;
    gemm_kernel<<<blocks2, 256, 0, stream>>>(out, W, n);
  }
}

// Round 10
// 83.261 us; speedup vs baseline: 1.6295x; 1.0090x over previous
//
#include <hip/hip_runtime.h>
#include <hip/hip_bf16.h>

#define D 128
#define TM 32
#define PAD 8

typedef unsigned int u32;
typedef unsigned short u16;
typedef __attribute__((ext_vector_type(8))) short short8;
typedef __attribute__((ext_vector_type(4))) float f32x4;
typedef __attribute__((ext_vector_type(4))) unsigned int u32x4;
typedef __attribute__((ext_vector_type(4))) unsigned short u16x4;

static __device__ __forceinline__ u16 f2b(float x) {
  __hip_bfloat16 b = __float2bfloat16(x);
  return *reinterpret_cast<u16*>(&b);
}
static __device__ __forceinline__ float u2f(u32 x) { return __uint_as_float(x); }

// ---------- bf16 fast path ----------

// Wt[c,k] = bf16(W[k,c])  (run once)
__global__ __launch_bounds__(256) void cvt_w(const float* __restrict__ W,
                                             u16* __restrict__ Wt) {
  int i = blockIdx.x * 256 + threadIdx.x;
  if (i >= D * D) return;
  int k = i >> 7, c = i & (D - 1);
  Wt[c * D + k] = f2b(W[k * D + c]);
}

// Yb[r,:] = bf16( src_norm[r] * (X[r,:] @ W) )   (64-row tile per block)
__global__ __launch_bounds__(256) void gemm_xw(
    const float* __restrict__ X, const float* __restrict__ sn,
    const u16* __restrict__ Wt, u16* __restrict__ Yb, int n) {
  __shared__ u16 Bsl[D][D + PAD];
  __shared__ u16 Asl[64][D + PAD];
  int tid = threadIdx.x;
  int r0 = blockIdx.x * 64;

#pragma unroll
  for (int p = 0; p < 8; ++p) {  // stage Wt (32 KB) - clean 16-B copies
    int t = p * 256 + tid;
    int r = t >> 4, c = (t & 15) << 3;
    *reinterpret_cast<uint4*>(&Bsl[r][c]) =
        *reinterpret_cast<const uint4*>(Wt + r * D + c);
  }
#pragma unroll
  for (int p = 0; p < 8; ++p) {  // stage A tile: f32 load, ns scale, cvt
    int idx = p * 256 + tid;
    int row = idx >> 5, c0 = (idx & 31) << 2;
    int gr = r0 + row;
    if (gr >= n) gr = n - 1;
    float ns = sn[gr];
    f32x4 v = *reinterpret_cast<const f32x4*>(X + (size_t)gr * D + c0);
    u16x4 o;
    o.x = f2b(v.x * ns); o.y = f2b(v.y * ns);
    o.z = f2b(v.z * ns); o.w = f2b(v.w * ns);
    *reinterpret_cast<u16x4*>(&Asl[row][c0]) = o;
  }
  __syncthreads();

  int wv = tid >> 6, lane = tid & 63;
  int lr = lane & 15, lg = lane >> 4;
  int arow = wv * 16 + lr;

  f32x4 acc[8] = {};
#pragma unroll
  for (int ks = 0; ks < 4; ++ks) {
    int k0 = ks * 32 + lg * 4;
    union { uint2 u[2]; short8 s; } pa;
    pa.u[0] = *reinterpret_cast<const uint2*>(&Asl[arow][k0]);
    pa.u[1] = *reinterpret_cast<const uint2*>(&Asl[arow][k0 + 16]);
#pragma unroll
    for (int nn = 0; nn < 8; ++nn) {
      union { uint2 u[2]; short8 s; } pb;
      pb.u[0] = *reinterpret_cast<const uint2*>(&Bsl[nn * 16 + lr][k0]);
      pb.u[1] = *reinterpret_cast<const uint2*>(&Bsl[nn * 16 + lr][k0 + 16]);
      acc[nn] = __builtin_amdgcn_mfma_f32_16x16x32_bf16(pa.s, pb.s, acc[nn], 0, 0, 0);
    }
  }

  __syncthreads();  // Asl reads done; reuse for bf16 output repack
#pragma unroll
  for (int nn = 0; nn < 8; ++nn)
#pragma unroll
    for (int r = 0; r < 4; ++r)
      Asl[wv * 16 + lg * 4 + r][nn * 16 + lr] = f2b(acc[nn][r]);
  __syncthreads();

#pragma unroll
  for (int p = 0; p < 4; ++p) {  // coalesced 16-B NT stores
    int idx = p * 256 + tid;
    int row = idx >> 4, c8 = (idx & 15) << 3;
    int gr = r0 + row;
    if (gr < n)
      __builtin_nontemporal_store(
          *reinterpret_cast<const u32x4*>(&Asl[row][c8]),
          reinterpret_cast<u32x4*>(Yb + (size_t)gr * D + c8));
  }
}

#define ACC8(r)                                             \
  a0 += u2f(r.x << 16); a1 += u2f(r.x & 0xffff0000u);       \
  a2 += u2f(r.y << 16); a3 += u2f(r.y & 0xffff0000u);       \
  a4 += u2f(r.z << 16); a5 += u2f(r.z & 0xffff0000u);       \
  a6 += u2f(r.w << 16); a7 += u2f(r.w & 0xffff0000u);

// out[node,:] = dst_norm[node] * sum_e Yb[src[e],:]  (f32 output)
// 16 lanes/node. Fast path (deg==16): bitonic-sort the 16 srcs across the
// 16-lane group and gather in ascending-src order -> concurrent blocks sweep
// the Yb table coherently, raising per-XCD L2 hit rate.
__global__ __launch_bounds__(256) void agg_final(
    const int* __restrict__ edge_ptr, const int* __restrict__ src_edges,
    const float* __restrict__ dst_norm, const u16* __restrict__ Yb,
    float* __restrict__ out, int n_nodes) {
  int gid = blockIdx.x * 256 + threadIdx.x;
  int node = gid >> 4;
  if (node >= n_nodes) return;
  int ll = threadIdx.x & 15;
  int fo = ll << 3;
  const u16* base = Yb + fo;
  float a0 = 0, a1 = 0, a2 = 0, a3 = 0, a4 = 0, a5 = 0, a6 = 0, a7 = 0;
  int e0 = edge_ptr[node], e1 = edge_ptr[node + 1];
  int d = e1 - e0;
  if (d == 16) {
    int v = src_edges[e0 + ll];  // lane ll holds edge ll's src
    // bitonic ascending sort of 16 values across the 16-lane group
#pragma unroll
    for (int k = 2; k <= 16; k <<= 1) {
#pragma unroll
      for (int j = k >> 1; j > 0; j >>= 1) {
        int v2 = __shfl_xor(v, j, 16);
        bool keepMin = (((ll & k) == 0) == ((ll & j) == 0));
        v = keepMin ? min(v, v2) : max(v, v2);
      }
    }
#pragma unroll
    for (int j = 0; j < 16; j += 4) {
      int s0 = __shfl(v, j + 0, 16);
      int s1 = __shfl(v, j + 1, 16);
      int s2 = __shfl(v, j + 2, 16);
      int s3 = __shfl(v, j + 3, 16);
      uint4 r0v = *reinterpret_cast<const uint4*>(base + (size_t)s0 * D);
      uint4 r1v = *reinterpret_cast<const uint4*>(base + (size_t)s1 * D);
      uint4 r2v = *reinterpret_cast<const uint4*>(base + (size_t)s2 * D);
      uint4 r3v = *reinterpret_cast<const uint4*>(base + (size_t)s3 * D);
      ACC8(r0v); ACC8(r1v); ACC8(r2v); ACC8(r3v);
    }
  } else {
    int e = e0;
    for (; e + 4 <= e1; e += 4) {
      int s0 = src_edges[e + 0], s1 = src_edges[e + 1];
      int s2 = src_edges[e + 2], s3 = src_edges[e + 3];
      uint4 r0v = *reinterpret_cast<const uint4*>(base + (size_t)s0 * D);
      uint4 r1v = *reinterpret_cast<const uint4*>(base + (size_t)s1 * D);
      uint4 r2v = *reinterpret_cast<const uint4*>(base + (size_t)s2 * D);
      uint4 r3v = *reinterpret_cast<const uint4*>(base + (size_t)s3 * D);
      ACC8(r0v); ACC8(r1v); ACC8(r2v); ACC8(r3v);
    }
    for (; e < e1; ++e) {
      int s = src_edges[e];
      uint4 rv = *reinterpret_cast<const uint4*>(base + (size_t)s * D);
      ACC8(rv);
    }
  }
  float nd = dst_norm[node];
  f32x4 o0 = {a0 * nd, a1 * nd, a2 * nd, a3 * nd};
  f32x4 o1 = {a4 * nd, a5 * nd, a6 * nd, a7 * nd};
  float* dst = out + (size_t)node * D + fo;
  __builtin_nontemporal_store(o0, reinterpret_cast<f32x4*>(dst));
  __builtin_nontemporal_store(o1, reinterpret_cast<f32x4*>(dst + 4));
}

// ---------- f32 fallback path (known-good) ----------

__global__ __launch_bounds__(256) void agg_kernel(
    const int* __restrict__ edge_ptr, const int* __restrict__ src_edges,
    const float* __restrict__ src_norm, const float* __restrict__ dst_norm,
    const float* __restrict__ X, float* __restrict__ agg, int n_nodes) {
  int gid = blockIdx.x * 256 + threadIdx.x;
  int node = gid >> 5;
  if (node >= n_nodes) return;
  int fo = (gid & 31) << 2;
  int e0 = edge_ptr[node];
  int e1 = edge_ptr[node + 1];
  float ax = 0.f, ay = 0.f, az = 0.f, aw = 0.f;
  for (int e = e0; e < e1; ++e) {
    int s = src_edges[e];
    float ns = src_norm[s];
    float4 v = *reinterpret_cast<const float4*>(X + (size_t)s * D + fo);
    ax = fmaf(ns, v.x, ax); ay = fmaf(ns, v.y, ay);
    az = fmaf(ns, v.z, az); aw = fmaf(ns, v.w, aw);
  }
  float nd = dst_norm[node];
  float4 r = make_float4(ax * nd, ay * nd, az * nd, aw * nd);
  *reinterpret_cast<float4*>(agg + (size_t)node * D + fo) = r;
}

#define FMA4(acc, sv, wv)            \
  acc.x = fmaf(sv, wv.x, acc.x);     \
  acc.y = fmaf(sv, wv.y, acc.y);     \
  acc.z = fmaf(sv, wv.z, acc.z);     \
  acc.w = fmaf(sv, wv.w, acc.w);

__global__ __launch_bounds__(256) void gemm_kernel(
    float* __restrict__ io, const float* __restrict__ W, int n_rows) {
  __shared__ float Wl[D][D];
  __shared__ float Al[TM][D];
  int tid = threadIdx.x;
  for (int i = tid * 4; i < D * D; i += 1024) {
    *reinterpret_cast<float4*>(&Wl[0][0] + i) =
        *reinterpret_cast<const float4*>(W + i);
  }
  int row0 = blockIdx.x * TM;
  for (int i = tid * 4; i < TM * D; i += 1024) {
    int r = i >> 7, c = i & (D - 1);
    if (row0 + r < n_rows)
      *reinterpret_cast<float4*>(&Al[r][c]) =
          *reinterpret_cast<const float4*>(io + (size_t)(row0 + r) * D + c);
  }
  __syncthreads();

  int cg = (tid & 31) * 4;
  int rb = (tid >> 5) * 4;
  float4 acc0 = {0, 0, 0, 0}, acc1 = {0, 0, 0, 0};
  float4 acc2 = {0, 0, 0, 0}, acc3 = {0, 0, 0, 0};

#pragma unroll 4
  for (int k = 0; k < D; k += 4) {
    float4 w0 = *reinterpret_cast<const float4*>(&Wl[k + 0][cg]);
    float4 w1 = *reinterpret_cast<const float4*>(&Wl[k + 1][cg]);
    float4 w2 = *reinterpret_cast<const float4*>(&Wl[k + 2][cg]);
    float4 w3 = *reinterpret_cast<const float4*>(&Wl[k + 3][cg]);
    float4 a0 = *reinterpret_cast<const float4*>(&Al[rb + 0][k]);
    float4 a1 = *reinterpret_cast<const float4*>(&Al[rb + 1][k]);
    float4 a2 = *reinterpret_cast<const float4*>(&Al[rb + 2][k]);
    float4 a3 = *reinterpret_cast<const float4*>(&Al[rb + 3][k]);
    FMA4(acc0, a0.x, w0); FMA4(acc0, a0.y, w1); FMA4(acc0, a0.z, w2); FMA4(acc0, a0.w, w3);
    FMA4(acc1, a1.x, w0); FMA4(acc1, a1.y, w1); FMA4(acc1, a1.z, w2); FMA4(acc1, a1.w, w3);
    FMA4(acc2, a2.x, w0); FMA4(acc2, a2.y, w1); FMA4(acc2, a2.z, w2); FMA4(acc2, a2.w, w3);
    FMA4(acc3, a3.x, w0); FMA4(acc3, a3.y, w1); FMA4(acc3, a3.z, w2); FMA4(acc3, a3.w, w3);
  }

  int r0 = row0 + rb;
  if (r0 + 0 < n_rows) *reinterpret_cast<float4*>(io + (size_t)(r0 + 0) * D + cg) = acc0;
  if (r0 + 1 < n_rows) *reinterpret_cast<float4*>(io + (size_t)(r0 + 1) * D + cg) = acc1;
  if (r0 + 2 < n_rows) *reinterpret_cast<float4*>(io + (size_t)(r0 + 2) * D + cg) = acc2;
  if (r0 + 3 < n_rows) *reinterpret_cast<float4*>(io + (size_t)(r0 + 3) * D + cg) = acc3;
}

extern "C" void kernel_launch(void* const* d_in, const int* in_sizes, int n_in,
                              void* d_out, int out_size, void* d_ws, size_t ws_size,
                              hipStream_t stream) {
  const int* edge_ptr = (const int*)d_in[0];
  const int* src_edges = (const int*)d_in[1];
  const float* src_norm = (const float*)d_in[2];
  const float* dst_norm = (const float*)d_in[3];
  const float* X = (const float*)d_in[5];
  const float* W = (const float*)d_in[6];
  float* out = (float*)d_out;
  int n = in_sizes[2];  // src_norm_degs has N elements

  size_t need = (size_t)n * D * sizeof(u16) + (size_t)D * D * sizeof(u16);
  if (ws_size >= need) {
    u16* Yb = (u16*)d_ws;
    u16* Wt = Yb + (size_t)n * D;
    cvt_w<<<(D * D + 255) / 256, 256, 0, stream>>>(W, Wt);
    gemm_xw<<<(n + 63) / 64, 256, 0, stream>>>(X, src_norm, Wt, Yb, n);
    agg_final<<<(n * 16 + 255) / 256, 256, 0, stream>>>(edge_ptr, src_edges,
                                                        dst_norm, Yb, out, n);
  } else {
    int blocks1 = (n * 32 + 255) / 256;
    agg_kernel<<<blocks1, 256, 0, stream>>>(edge_ptr, src_edges, src_norm,
                                            dst_norm, X, out, n);
    int blocks2 = (n + TM - 1) / TM;
    gemm_kernel<<<blocks2, 256, 0, stream>>>(out, W, n);
  }
}

// Round 11
// 60.786 us; speedup vs baseline: 2.2320x; 1.3697x over previous
//
#include <hip/hip_runtime.h>
#include <hip/hip_bf16.h>

#define D 128
#define TM 32
#define PAD 8

typedef unsigned int u32;
typedef unsigned short u16;
typedef __attribute__((ext_vector_type(8))) short short8;
typedef __attribute__((ext_vector_type(4))) float f32x4;
typedef __attribute__((ext_vector_type(4))) unsigned int u32x4;
typedef __attribute__((ext_vector_type(4))) unsigned short u16x4;

static __device__ __forceinline__ u16 f2b(float x) {
  __hip_bfloat16 b = __float2bfloat16(x);
  return *reinterpret_cast<u16*>(&b);
}
static __device__ __forceinline__ float u2f(u32 x) { return __uint_as_float(x); }

// ---------- int8 fast path ----------

// Wt[c,k] = bf16(W[k,c])  (run once)
__global__ __launch_bounds__(256) void cvt_w(const float* __restrict__ W,
                                             u16* __restrict__ Wt) {
  int i = blockIdx.x * 256 + threadIdx.x;
  if (i >= D * D) return;
  int k = i >> 7, c = i & (D - 1);
  Wt[c * D + k] = f2b(W[k * D + c]);
}

// Yq[r][c] = int8( round( y[r][c] * 127/amax_r ) ),  ysc[r] = amax_r/127
// where y[r,:] = src_norm[r] * (X[r,:] @ W).  64-row tile per block.
__global__ __launch_bounds__(256) void gemm_xw(
    const float* __restrict__ X, const float* __restrict__ sn,
    const u16* __restrict__ Wt, signed char* __restrict__ Yq,
    float* __restrict__ ysc, int n) {
  __shared__ u16 Bsl[D][D + PAD];
  __shared__ u16 Asl[64][D + PAD];
  int tid = threadIdx.x;
  int r0 = blockIdx.x * 64;

#pragma unroll
  for (int p = 0; p < 8; ++p) {  // stage Wt (32 KB) - clean 16-B copies
    int t = p * 256 + tid;
    int r = t >> 4, c = (t & 15) << 3;
    *reinterpret_cast<uint4*>(&Bsl[r][c]) =
        *reinterpret_cast<const uint4*>(Wt + r * D + c);
  }
#pragma unroll
  for (int p = 0; p < 8; ++p) {  // stage A tile: f32 load, ns scale, cvt
    int idx = p * 256 + tid;
    int row = idx >> 5, c0 = (idx & 31) << 2;
    int gr = r0 + row;
    if (gr >= n) gr = n - 1;
    float ns = sn[gr];
    f32x4 v = *reinterpret_cast<const f32x4*>(X + (size_t)gr * D + c0);
    u16x4 o;
    o.x = f2b(v.x * ns); o.y = f2b(v.y * ns);
    o.z = f2b(v.z * ns); o.w = f2b(v.w * ns);
    *reinterpret_cast<u16x4*>(&Asl[row][c0]) = o;
  }
  __syncthreads();

  int wv = tid >> 6, lane = tid & 63;
  int lr = lane & 15, lg = lane >> 4;
  int arow = wv * 16 + lr;

  f32x4 acc[8] = {};
#pragma unroll
  for (int ks = 0; ks < 4; ++ks) {
    int k0 = ks * 32 + lg * 4;
    union { uint2 u[2]; short8 s; } pa;
    pa.u[0] = *reinterpret_cast<const uint2*>(&Asl[arow][k0]);
    pa.u[1] = *reinterpret_cast<const uint2*>(&Asl[arow][k0 + 16]);
#pragma unroll
    for (int nn = 0; nn < 8; ++nn) {
      union { uint2 u[2]; short8 s; } pb;
      pb.u[0] = *reinterpret_cast<const uint2*>(&Bsl[nn * 16 + lr][k0]);
      pb.u[1] = *reinterpret_cast<const uint2*>(&Bsl[nn * 16 + lr][k0 + 16]);
      acc[nn] = __builtin_amdgcn_mfma_f32_16x16x32_bf16(pa.s, pb.s, acc[nn], 0, 0, 0);
    }
  }

  __syncthreads();  // Asl reads done; repack result as bf16 rows
#pragma unroll
  for (int nn = 0; nn < 8; ++nn)
#pragma unroll
    for (int r = 0; r < 4; ++r)
      Asl[wv * 16 + lg * 4 + r][nn * 16 + lr] = f2b(acc[nn][r]);
  __syncthreads();

  // int8 quantization pass: 4 threads per row, 32 cols each.
  {
    int row = tid >> 2, qt = tid & 3;
    int gr = r0 + row;
    float vals[32];
    float amax = 0.f;
#pragma unroll
    for (int i = 0; i < 4; ++i) {
      uint4 w = *reinterpret_cast<const uint4*>(&Asl[row][qt * 32 + i * 8]);
      u32 ws[4] = {w.x, w.y, w.z, w.w};
#pragma unroll
      for (int h = 0; h < 4; ++h) {
        float v0 = u2f(ws[h] << 16);
        float v1 = u2f(ws[h] & 0xffff0000u);
        vals[i * 8 + h * 2 + 0] = v0;
        vals[i * 8 + h * 2 + 1] = v1;
        amax = fmaxf(amax, fmaxf(fabsf(v0), fabsf(v1)));
      }
    }
    amax = fmaxf(amax, __shfl_xor(amax, 1, 4));
    amax = fmaxf(amax, __shfl_xor(amax, 2, 4));
    float inv = amax > 0.f ? 127.0f / amax : 0.f;
    u32 pk[8];
#pragma unroll
    for (int i = 0; i < 8; ++i) {
      u32 b0 = (u32)((int)rintf(vals[i * 4 + 0] * inv)) & 0xffu;
      u32 b1 = (u32)((int)rintf(vals[i * 4 + 1] * inv)) & 0xffu;
      u32 b2 = (u32)((int)rintf(vals[i * 4 + 2] * inv)) & 0xffu;
      u32 b3 = (u32)((int)rintf(vals[i * 4 + 3] * inv)) & 0xffu;
      pk[i] = b0 | (b1 << 8) | (b2 << 16) | (b3 << 24);
    }
    if (gr < n) {
      u32x4 o0 = {pk[0], pk[1], pk[2], pk[3]};
      u32x4 o1 = {pk[4], pk[5], pk[6], pk[7]};
      u32* dst = reinterpret_cast<u32*>(Yq + (size_t)gr * D + qt * 32);
      __builtin_nontemporal_store(o0, reinterpret_cast<u32x4*>(dst));
      __builtin_nontemporal_store(o1, reinterpret_cast<u32x4*>(dst + 4));
      if (qt == 0) ysc[gr] = amax * (1.0f / 127.0f);
    }
  }
}

// int8 decode-accumulate: 8 bytes of q (uint2), scale sc
#define ACCQ(q, sc)                                              \
  a0 = fmaf(sc, (float)((int)((q).x << 24) >> 24), a0);          \
  a1 = fmaf(sc, (float)((int)((q).x << 16) >> 24), a1);          \
  a2 = fmaf(sc, (float)((int)((q).x << 8) >> 24), a2);           \
  a3 = fmaf(sc, (float)((int)(q).x >> 24), a3);                  \
  a4 = fmaf(sc, (float)((int)((q).y << 24) >> 24), a4);          \
  a5 = fmaf(sc, (float)((int)((q).y << 16) >> 24), a5);          \
  a6 = fmaf(sc, (float)((int)(q).y << 8 >> 24), a6);             \
  a7 = fmaf(sc, (float)((int)(q).y >> 24), a7);

// out[node,:] = dst_norm[node] * sum_e ysc[s]*Yq[s,:]  (f32 output)
// 16 lanes/node, 8 int8 (8 B) per lane, 4-deep unroll.
__global__ __launch_bounds__(256) void agg_final(
    const int* __restrict__ edge_ptr, const int* __restrict__ src_edges,
    const float* __restrict__ dst_norm, const signed char* __restrict__ Yq,
    const float* __restrict__ ysc, float* __restrict__ out, int n_nodes) {
  int gid = blockIdx.x * 256 + threadIdx.x;
  int node = gid >> 4;
  if (node >= n_nodes) return;
  int ll = threadIdx.x & 15;
  int fo = ll << 3;
  const signed char* base = Yq + fo;
  float a0 = 0, a1 = 0, a2 = 0, a3 = 0, a4 = 0, a5 = 0, a6 = 0, a7 = 0;
  int e0 = edge_ptr[node], e1 = edge_ptr[node + 1];
  int e = e0;
  for (; e + 4 <= e1; e += 4) {
    int s0 = src_edges[e + 0], s1 = src_edges[e + 1];
    int s2 = src_edges[e + 2], s3 = src_edges[e + 3];
    uint2 q0 = *reinterpret_cast<const uint2*>(base + (size_t)s0 * D);
    uint2 q1 = *reinterpret_cast<const uint2*>(base + (size_t)s1 * D);
    uint2 q2 = *reinterpret_cast<const uint2*>(base + (size_t)s2 * D);
    uint2 q3 = *reinterpret_cast<const uint2*>(base + (size_t)s3 * D);
    float c0 = ysc[s0], c1 = ysc[s1], c2 = ysc[s2], c3 = ysc[s3];
    ACCQ(q0, c0); ACCQ(q1, c1); ACCQ(q2, c2); ACCQ(q3, c3);
  }
  for (; e < e1; ++e) {
    int s = src_edges[e];
    uint2 q = *reinterpret_cast<const uint2*>(base + (size_t)s * D);
    float c = ysc[s];
    ACCQ(q, c);
  }
  float nd = dst_norm[node];
  f32x4 o0 = {a0 * nd, a1 * nd, a2 * nd, a3 * nd};
  f32x4 o1 = {a4 * nd, a5 * nd, a6 * nd, a7 * nd};
  float* dst = out + (size_t)node * D + fo;
  __builtin_nontemporal_store(o0, reinterpret_cast<f32x4*>(dst));
  __builtin_nontemporal_store(o1, reinterpret_cast<f32x4*>(dst + 4));
}

// ---------- f32 fallback path (known-good) ----------

__global__ __launch_bounds__(256) void agg_kernel(
    const int* __restrict__ edge_ptr, const int* __restrict__ src_edges,
    const float* __restrict__ src_norm, const float* __restrict__ dst_norm,
    const float* __restrict__ X, float* __restrict__ agg, int n_nodes) {
  int gid = blockIdx.x * 256 + threadIdx.x;
  int node = gid >> 5;
  if (node >= n_nodes) return;
  int fo = (gid & 31) << 2;
  int e0 = edge_ptr[node];
  int e1 = edge_ptr[node + 1];
  float ax = 0.f, ay = 0.f, az = 0.f, aw = 0.f;
  for (int e = e0; e < e1; ++e) {
    int s = src_edges[e];
    float ns = src_norm[s];
    float4 v = *reinterpret_cast<const float4*>(X + (size_t)s * D + fo);
    ax = fmaf(ns, v.x, ax); ay = fmaf(ns, v.y, ay);
    az = fmaf(ns, v.z, az); aw = fmaf(ns, v.w, aw);
  }
  float nd = dst_norm[node];
  float4 r = make_float4(ax * nd, ay * nd, az * nd, aw * nd);
  *reinterpret_cast<float4*>(agg + (size_t)node * D + fo) = r;
}

#define FMA4(acc, sv, wv)            \
  acc.x = fmaf(sv, wv.x, acc.x);     \
  acc.y = fmaf(sv, wv.y, acc.y);     \
  acc.z = fmaf(sv, wv.z, acc.z);     \
  acc.w = fmaf(sv, wv.w, acc.w);

__global__ __launch_bounds__(256) void gemm_kernel(
    float* __restrict__ io, const float* __restrict__ W, int n_rows) {
  __shared__ float Wl[D][D];
  __shared__ float Al[TM][D];
  int tid = threadIdx.x;
  for (int i = tid * 4; i < D * D; i += 1024) {
    *reinterpret_cast<float4*>(&Wl[0][0] + i) =
        *reinterpret_cast<const float4*>(W + i);
  }
  int row0 = blockIdx.x * TM;
  for (int i = tid * 4; i < TM * D; i += 1024) {
    int r = i >> 7, c = i & (D - 1);
    if (row0 + r < n_rows)
      *reinterpret_cast<float4*>(&Al[r][c]) =
          *reinterpret_cast<const float4*>(io + (size_t)(row0 + r) * D + c);
  }
  __syncthreads();

  int cg = (tid & 31) * 4;
  int rb = (tid >> 5) * 4;
  float4 acc0 = {0, 0, 0, 0}, acc1 = {0, 0, 0, 0};
  float4 acc2 = {0, 0, 0, 0}, acc3 = {0, 0, 0, 0};

#pragma unroll 4
  for (int k = 0; k < D; k += 4) {
    float4 w0 = *reinterpret_cast<const float4*>(&Wl[k + 0][cg]);
    float4 w1 = *reinterpret_cast<const float4*>(&Wl[k + 1][cg]);
    float4 w2 = *reinterpret_cast<const float4*>(&Wl[k + 2][cg]);
    float4 w3 = *reinterpret_cast<const float4*>(&Wl[k + 3][cg]);
    float4 a0 = *reinterpret_cast<const float4*>(&Al[rb + 0][k]);
    float4 a1 = *reinterpret_cast<const float4*>(&Al[rb + 1][k]);
    float4 a2 = *reinterpret_cast<const float4*>(&Al[rb + 2][k]);
    float4 a3 = *reinterpret_cast<const float4*>(&Al[rb + 3][k]);
    FMA4(acc0, a0.x, w0); FMA4(acc0, a0.y, w1); FMA4(acc0, a0.z, w2); FMA4(acc0, a0.w, w3);
    FMA4(acc1, a1.x, w0); FMA4(acc1, a1.y, w1); FMA4(acc1, a1.z, w2); FMA4(acc1, a1.w, w3);
    FMA4(acc2, a2.x, w0); FMA4(acc2, a2.y, w1); FMA4(acc2, a2.z, w2); FMA4(acc2, a2.w, w3);
    FMA4(acc3, a3.x, w0); FMA4(acc3, a3.y, w1); FMA4(acc3, a3.z, w2); FMA4(acc3, a3.w, w3);
  }

  int r0 = row0 + rb;
  if (r0 + 0 < n_rows) *reinterpret_cast<float4*>(io + (size_t)(r0 + 0) * D + cg) = acc0;
  if (r0 + 1 < n_rows) *reinterpret_cast<float4*>(io + (size_t)(r0 + 1) * D + cg) = acc1;
  if (r0 + 2 < n_rows) *reinterpret_cast<float4*>(io + (size_t)(r0 + 2) * D + cg) = acc2;
  if (r0 + 3 < n_rows) *reinterpret_cast<float4*>(io + (size_t)(r0 + 3) * D + cg) = acc3;
}

extern "C" void kernel_launch(void* const* d_in, const int* in_sizes, int n_in,
                              void* d_out, int out_size, void* d_ws, size_t ws_size,
                              hipStream_t stream) {
  const int* edge_ptr = (const int*)d_in[0];
  const int* src_edges = (const int*)d_in[1];
  const float* src_norm = (const float*)d_in[2];
  const float* dst_norm = (const float*)d_in[3];
  const float* X = (const float*)d_in[5];
  const float* W = (const float*)d_in[6];
  float* out = (float*)d_out;
  int n = in_sizes[2];  // src_norm_degs has N elements

  size_t need = (size_t)n * D + (size_t)n * sizeof(float) +
                (size_t)D * D * sizeof(u16);
  if (ws_size >= need) {
    signed char* Yq = (signed char*)d_ws;
    float* ysc = (float*)(Yq + (size_t)n * D);
    u16* Wt = (u16*)(ysc + n);
    cvt_w<<<(D * D + 255) / 256, 256, 0, stream>>>(W, Wt);
    gemm_xw<<<(n + 63) / 64, 256, 0, stream>>>(X, src_norm, Wt, Yq, ysc, n);
    agg_final<<<(n * 16 + 255) / 256, 256, 0, stream>>>(edge_ptr, src_edges,
                                                        dst_norm, Yq, ysc, out, n);
  } else {
    int blocks1 = (n * 32 + 255) / 256;
    agg_kernel<<<blocks1, 256, 0, stream>>>(edge_ptr, src_edges, src_norm,
                                            dst_norm, X, out, n);
    int blocks2 = (n + TM - 1) / TM;
    gemm_kernel<<<blocks2, 256, 0, stream>>>(out, W, n);
  }
}